// Round 3
// baseline (294.845 us; speedup 1.0000x reference)
//
#include <hip/hip_runtime.h>

// Problem constants (from reference)
constexpr int T   = 5;
constexpr int BS  = 32;
constexpr int C   = 64;
constexpr int H   = 64;
constexpr int W   = 64;
constexpr int HW  = H * W;        // 4096  (= 2^12)
constexpr int CHW = C * HW;       // 262144 (= 2^18)
constexpr int N   = T * BS;       // 160
constexpr float TAU = 0.5f;
// gamma computed in double then cast to f32, matching jax weak-type promotion
constexpr float GAMMA = (float)(0.1 / 49.0);

// native vector type usable with __builtin_nontemporal_{load,store}
typedef float v4f __attribute__((ext_vector_type(4)));

// ---------------------------------------------------------------------------
// Kernel 1: block_mask[n,h,w] = 1 - maxpool7x7_SAME( mask_noise[n,h,w] < GAMMA )
// 4 row-chunks per plane (16 output rows each, 3-row halo) -> 640 blocks so
// the whole GPU participates. Separable max: row-window max in LDS, then
// column-window max over the halo'd chunk.  (~4-5 us, not the lever.)
// ---------------------------------------------------------------------------
__global__ void __launch_bounds__(256)
block_mask_kernel(const float* __restrict__ mask_noise,
                  float* __restrict__ block_mask) {
    __shared__ float bin[22][W];
    __shared__ float rowmax[22][W];
    const int n     = blockIdx.x >> 2;
    const int chunk = blockIdx.x & 3;
    const int r0    = chunk * 16;                 // first output row
    const int gh0   = max(r0 - 3, 0);             // first input row (global)
    const int gh1   = min(r0 + 15 + 3, H - 1);    // last input row (global)
    const int nrows = gh1 - gh0 + 1;              // <= 22

    const float* mn = mask_noise + (size_t)n * HW + (size_t)gh0 * W;

    // binarize halo'd rows into LDS
    for (int i = threadIdx.x; i < nrows * W; i += blockDim.x) {
        bin[i >> 6][i & 63] = (mn[i] < GAMMA) ? 1.0f : 0.0f;
    }
    __syncthreads();

    // row-wise max over w-window [w-3, w+3] clamped
    for (int i = threadIdx.x; i < nrows * W; i += blockDim.x) {
        const int h = i >> 6, w = i & 63;
        const int w0 = max(w - 3, 0), w1 = min(w + 3, W - 1);
        float m = 0.0f;
        for (int ww = w0; ww <= w1; ++ww) m = fmaxf(m, bin[h][ww]);
        rowmax[h][w] = m;
    }
    __syncthreads();

    // col-wise max over h-window, write 1 - pooled for the 16 output rows
    for (int i = threadIdx.x; i < 16 * W; i += blockDim.x) {
        const int ho = r0 + (i >> 6), w = i & 63;
        const int h0 = max(ho - 3, 0) - gh0, h1 = min(ho + 3, H - 1) - gh0;
        float m = 0.0f;
        for (int hh = h0; hh <= h1; ++hh) m = fmaxf(m, rowmax[hh][w]);
        block_mask[(size_t)n * HW + (size_t)ho * W + w] = 1.0f - m;
    }
}

// ---------------------------------------------------------------------------
// Kernel 2: LIF scan, channel-tiled.
//
// Key observation: block_mask[nb, hw] and vth[nb] are independent of c. The
// previous version relied on L2 to serve bm 64x per plane, but the out
// write-allocate stream churns each XCD's 4 MiB L2, so bm lines get evicted
// between uses -> up to 168 MB of hidden HBM re-fetch (+26 us).
//
// This version makes the reuse ARCHITECTURAL: each thread owns the same
// (b, hw) vec4 across 8 consecutive channels. Per t-step it loads bm and vth
// ONCE and applies them to 8 x->out streams. bm demand drops 8x; per-byte
// address/issue work drops too. x/out instructions keep the 16B/lane
// fully-coalesced pattern (round 1 showed splitting that costs ~5%).
//
// u state: 8 x vec4 = 32 VGPR, all indices compile-time (fully unrolled).
// Grid: 1024 blocks x 256 threads; the 6.6 TB/s fill kernels run at ~10%
// occupancy, so this saturates the memory path.
//
// Numerics match the fp32 reference exactly:
//   0.5f*u is exact; (u - vt >= 0) <=> (u >= vt) in IEEE fp32; spike=1.0
//   so o = bm on spike, 0 otherwise.
// ---------------------------------------------------------------------------
constexpr int NC = 8;                      // channels per thread

__global__ void __launch_bounds__(256)
lif_kernel(const float* __restrict__ x,
           const float* __restrict__ vth,
           const float* __restrict__ block_mask,
           float* __restrict__ out) {
    // 4 blocks cover one (b, c-group) plane; block-uniform b and cg.
    const int group = blockIdx.x >> 2;             // 0..255 = (b, cg)
    const int b     = group >> 3;                  // scalar: group / (C/NC)
    const int cg    = group & 7;                   // scalar: group % (C/NC)
    const int hw    = ((blockIdx.x & 3) * 256 + threadIdx.x) * 4;
    const size_t cOff = (size_t)(cg * NC) * HW + hw;

    v4f u[NC];
#pragma unroll
    for (int k = 0; k < NC; ++k) u[k] = (v4f)(0.0f);

#pragma unroll
    for (int t = 0; t < T; ++t) {
        const int nb = t * BS + b;                 // scalar
        const float vt = vth[nb];                  // s_load broadcast
        const v4f m4 = *(const v4f*)(block_mask + (size_t)nb * HW + hw);
        const float* xp = x   + (size_t)nb * CHW + cOff;
        float*       op = out + (size_t)nb * CHW + cOff;

#pragma unroll
        for (int k = 0; k < NC; ++k) {
            const v4f x4 = __builtin_nontemporal_load(
                (const v4f*)(xp + (size_t)k * HW));
            v4f o4;
            u[k].x = TAU * u[k].x + x4.x;
            if (u[k].x >= vt) { o4.x = m4.x; u[k].x -= vt; } else { o4.x = 0.0f; }
            u[k].y = TAU * u[k].y + x4.y;
            if (u[k].y >= vt) { o4.y = m4.y; u[k].y -= vt; } else { o4.y = 0.0f; }
            u[k].z = TAU * u[k].z + x4.z;
            if (u[k].z >= vt) { o4.z = m4.z; u[k].z -= vt; } else { o4.z = 0.0f; }
            u[k].w = TAU * u[k].w + x4.w;
            if (u[k].w >= vt) { o4.w = m4.w; u[k].w -= vt; } else { o4.w = 0.0f; }
            *(v4f*)(op + (size_t)k * HW) = o4;     // plain cached store
        }
    }
}

extern "C" void kernel_launch(void* const* d_in, const int* in_sizes, int n_in,
                              void* d_out, int out_size, void* d_ws, size_t ws_size,
                              hipStream_t stream) {
    const float* x          = (const float*)d_in[0];   // [N, C, H, W]
    const float* vth        = (const float*)d_in[1];   // [N]
    const float* mask_noise = (const float*)d_in[2];   // [N, H, W]
    float* out = (float*)d_out;                        // [N, C, H, W]
    float* bm  = (float*)d_ws;                         // [N, H, W] scratch (2.62 MB)

    block_mask_kernel<<<N * 4, 256, 0, stream>>>(mask_noise, bm);

    const int blocks = (BS * CHW) / (4 * NC) / 256;    // 1024
    lif_kernel<<<blocks, 256, 0, stream>>>(x, vth, bm, out);
}

// Round 4
// 291.065 us; speedup vs baseline: 1.0130x; 1.0130x over previous
//
#include <hip/hip_runtime.h>

// Problem constants (from reference)
constexpr int T   = 5;
constexpr int BS  = 32;
constexpr int C   = 64;
constexpr int H   = 64;
constexpr int W   = 64;
constexpr int HW  = H * W;        // 4096  (= 2^12)
constexpr int CHW = C * HW;       // 262144 (= 2^18)
constexpr int N   = T * BS;       // 160
constexpr float TAU = 0.5f;
// gamma computed in double then cast to f32, matching jax weak-type promotion
constexpr float GAMMA = (float)(0.1 / 49.0);

typedef float v4f __attribute__((ext_vector_type(4)));

// ---------------------------------------------------------------------------
// Kernel 1: block_mask[n,h,w] = 1 - maxpool7x7_SAME( mask_noise[n,h,w] < GAMMA )
// 4 row-chunks per plane (16 output rows each, 3-row halo) -> 640 blocks so
// the whole GPU participates. Separable max: row-window max in LDS, then
// column-window max over the halo'd chunk.  (~4-5 us, not the lever.)
// ---------------------------------------------------------------------------
__global__ void __launch_bounds__(256)
block_mask_kernel(const float* __restrict__ mask_noise,
                  float* __restrict__ block_mask) {
    __shared__ float bin[22][W];
    __shared__ float rowmax[22][W];
    const int n     = blockIdx.x >> 2;
    const int chunk = blockIdx.x & 3;
    const int r0    = chunk * 16;                 // first output row
    const int gh0   = max(r0 - 3, 0);             // first input row (global)
    const int gh1   = min(r0 + 15 + 3, H - 1);    // last input row (global)
    const int nrows = gh1 - gh0 + 1;              // <= 22

    const float* mn = mask_noise + (size_t)n * HW + (size_t)gh0 * W;

    // binarize halo'd rows into LDS
    for (int i = threadIdx.x; i < nrows * W; i += blockDim.x) {
        bin[i >> 6][i & 63] = (mn[i] < GAMMA) ? 1.0f : 0.0f;
    }
    __syncthreads();

    // row-wise max over w-window [w-3, w+3] clamped
    for (int i = threadIdx.x; i < nrows * W; i += blockDim.x) {
        const int h = i >> 6, w = i & 63;
        const int w0 = max(w - 3, 0), w1 = min(w + 3, W - 1);
        float m = 0.0f;
        for (int ww = w0; ww <= w1; ++ww) m = fmaxf(m, bin[h][ww]);
        rowmax[h][w] = m;
    }
    __syncthreads();

    // col-wise max over h-window, write 1 - pooled for the 16 output rows
    for (int i = threadIdx.x; i < 16 * W; i += blockDim.x) {
        const int ho = r0 + (i >> 6), w = i & 63;
        const int h0 = max(ho - 3, 0) - gh0, h1 = min(ho + 3, H - 1) - gh0;
        float m = 0.0f;
        for (int hh = h0; hh <= h1; ++hh) m = fmaxf(m, rowmax[hh][w]);
        block_mask[(size_t)n * HW + (size_t)ho * W + w] = 1.0f - m;
    }
}

// ---------------------------------------------------------------------------
// Kernel 2: LIF scan. One thread owns 4 contiguous (b,c,h,w) cells; u carried
// in registers across the fully-unrolled T=5 loop.  (R2 structure = best
// measured, 287.5 us.)
//
// Policy-matrix history:
//   (NT load, NT store)     292.9 us
//   (NT load, plain store)  287.5 us   <- previous best
//   (plain, plain)          THIS ROUND (H11: nt loads are the slow stream;
//                           the 6.29 TB/s copy ceiling was measured with
//                           plain loads; bm L2-residency is worth ~0, so
//                           NT's cache-protection rationale is gone)
//
// b = blockIdx.x >> 8 is block-uniform (each block covers 1024 consecutive
// elements, CHW = 2^18) -> vth[nb] is an s_load broadcast; div/mod are masks.
//
// Numerics match the fp32 reference exactly:
//   0.5f*u is exact; (u - vt >= 0) <=> (u >= vt) in IEEE fp32.
// ---------------------------------------------------------------------------
__global__ void __launch_bounds__(256)
lif_kernel(const float* __restrict__ x,
           const float* __restrict__ vth,
           const float* __restrict__ block_mask,
           float* __restrict__ out) {
    const int tid = blockIdx.x * 256 + threadIdx.x;   // vec4 index
    const int e   = tid * 4;                          // element index in [0, BS*CHW)
    const int b   = blockIdx.x >> 8;                  // e / CHW, block-uniform (scalar)
    const int rem = e & (CHW - 1);                    // c*HW + hw
    const int hw  = e & (HW - 1);

    v4f u = (v4f)(0.0f);

#pragma unroll
    for (int t = 0; t < T; ++t) {
        const int nb = t * BS + b;                    // scalar
        const v4f x4 = *(const v4f*)(x + (size_t)nb * CHW + rem);   // plain cached load
        const v4f m4 = *(const v4f*)(block_mask + (size_t)nb * HW + hw);
        const float vt = vth[nb];                     // s_load broadcast

        v4f o4;
        u.x = TAU * u.x + x4.x;
        if (u.x >= vt) { o4.x = m4.x; u.x -= vt; } else { o4.x = 0.0f; }
        u.y = TAU * u.y + x4.y;
        if (u.y >= vt) { o4.y = m4.y; u.y -= vt; } else { o4.y = 0.0f; }
        u.z = TAU * u.z + x4.z;
        if (u.z >= vt) { o4.z = m4.z; u.z -= vt; } else { o4.z = 0.0f; }
        u.w = TAU * u.w + x4.w;
        if (u.w >= vt) { o4.w = m4.w; u.w -= vt; } else { o4.w = 0.0f; }

        *(v4f*)(out + (size_t)nb * CHW + rem) = o4;   // plain cached store
    }
}

extern "C" void kernel_launch(void* const* d_in, const int* in_sizes, int n_in,
                              void* d_out, int out_size, void* d_ws, size_t ws_size,
                              hipStream_t stream) {
    const float* x          = (const float*)d_in[0];   // [N, C, H, W]
    const float* vth        = (const float*)d_in[1];   // [N]
    const float* mask_noise = (const float*)d_in[2];   // [N, H, W]
    float* out = (float*)d_out;                        // [N, C, H, W]
    float* bm  = (float*)d_ws;                         // [N, H, W] scratch (2.62 MB)

    block_mask_kernel<<<N * 4, 256, 0, stream>>>(mask_noise, bm);

    const int nvec   = (BS * CHW) / 4;    // 2,097,152 float4 threads
    const int blocks = nvec / 256;        // 8192 blocks
    lif_kernel<<<blocks, 256, 0, stream>>>(x, vth, bm, out);
}

// Round 5
// 288.530 us; speedup vs baseline: 1.0219x; 1.0088x over previous
//
#include <hip/hip_runtime.h>

// Problem constants (from reference)
constexpr int T   = 5;
constexpr int BS  = 32;
constexpr int C   = 64;
constexpr int H   = 64;
constexpr int W   = 64;
constexpr int HW  = H * W;        // 4096  (= 2^12)
constexpr int CHW = C * HW;       // 262144 (= 2^18)
constexpr int N   = T * BS;       // 160
constexpr float TAU = 0.5f;
// gamma computed in double then cast to f32, matching jax weak-type promotion
constexpr float GAMMA = (float)(0.1 / 49.0);

// native vector type usable with __builtin_nontemporal_{load,store}
typedef float v4f __attribute__((ext_vector_type(4)));

// ---------------------------------------------------------------------------
// Kernel 1: block_mask[n,h,w] = 1 - maxpool7x7_SAME( mask_noise[n,h,w] < GAMMA )
// 4 row-chunks per plane (16 output rows each, 3-row halo) -> 640 blocks so
// the whole GPU participates. Separable max: row-window max in LDS, then
// column-window max over the halo'd chunk.  (~4-5 us, not the lever.)
// ---------------------------------------------------------------------------
__global__ void __launch_bounds__(256)
block_mask_kernel(const float* __restrict__ mask_noise,
                  float* __restrict__ block_mask) {
    __shared__ float bin[22][W];
    __shared__ float rowmax[22][W];
    const int n     = blockIdx.x >> 2;
    const int chunk = blockIdx.x & 3;
    const int r0    = chunk * 16;                 // first output row
    const int gh0   = max(r0 - 3, 0);             // first input row (global)
    const int gh1   = min(r0 + 15 + 3, H - 1);    // last input row (global)
    const int nrows = gh1 - gh0 + 1;              // <= 22

    const float* mn = mask_noise + (size_t)n * HW + (size_t)gh0 * W;

    // binarize halo'd rows into LDS
    for (int i = threadIdx.x; i < nrows * W; i += blockDim.x) {
        bin[i >> 6][i & 63] = (mn[i] < GAMMA) ? 1.0f : 0.0f;
    }
    __syncthreads();

    // row-wise max over w-window [w-3, w+3] clamped
    for (int i = threadIdx.x; i < nrows * W; i += blockDim.x) {
        const int h = i >> 6, w = i & 63;
        const int w0 = max(w - 3, 0), w1 = min(w + 3, W - 1);
        float m = 0.0f;
        for (int ww = w0; ww <= w1; ++ww) m = fmaxf(m, bin[h][ww]);
        rowmax[h][w] = m;
    }
    __syncthreads();

    // col-wise max over h-window, write 1 - pooled for the 16 output rows
    for (int i = threadIdx.x; i < 16 * W; i += blockDim.x) {
        const int ho = r0 + (i >> 6), w = i & 63;
        const int h0 = max(ho - 3, 0) - gh0, h1 = min(ho + 3, H - 1) - gh0;
        float m = 0.0f;
        for (int hh = h0; hh <= h1; ++hh) m = fmaxf(m, rowmax[hh][w]);
        block_mask[(size_t)n * HW + (size_t)ho * W + w] = 1.0f - m;
    }
}

// ---------------------------------------------------------------------------
// Kernel 2: LIF scan. One thread owns 4 contiguous (b,c,h,w) cells; u carried
// in registers across the fully-unrolled T=5 loop.
//
// FINAL config — best of the measured policy/structure matrix (287.5 us):
//   (NT load, NT store)        292.9
//   (NT load, plain store)     287.5   <- THIS
//   (plain load, plain store)  291.1
//   8-wide split               308.7   (stride-interleaved streams hurt)
//   channel-tiled (8c/thread)  294.8   (bm L2 re-fetch was not the gap)
//
// b = blockIdx.x >> 8 is block-uniform (each block covers 1024 consecutive
// elements, CHW = 2^18) -> vth[nb] is an s_load broadcast; div/mod are masks.
//
// Numerics match the fp32 reference exactly:
//   0.5f*u is exact; (u - vt >= 0) <=> (u >= vt) in IEEE fp32.
// ---------------------------------------------------------------------------
__global__ void __launch_bounds__(256)
lif_kernel(const float* __restrict__ x,
           const float* __restrict__ vth,
           const float* __restrict__ block_mask,
           float* __restrict__ out) {
    const int tid = blockIdx.x * 256 + threadIdx.x;   // vec4 index
    const int e   = tid * 4;                          // element index in [0, BS*CHW)
    const int b   = blockIdx.x >> 8;                  // e / CHW, block-uniform (scalar)
    const int rem = e & (CHW - 1);                    // c*HW + hw
    const int hw  = e & (HW - 1);

    v4f u = (v4f)(0.0f);

#pragma unroll
    for (int t = 0; t < T; ++t) {
        const int nb = t * BS + b;                    // scalar
        const v4f x4 = __builtin_nontemporal_load(
            (const v4f*)(x + (size_t)nb * CHW + rem));
        const v4f m4 = *(const v4f*)(block_mask + (size_t)nb * HW + hw);
        const float vt = vth[nb];                     // s_load broadcast

        v4f o4;
        u.x = TAU * u.x + x4.x;
        if (u.x >= vt) { o4.x = m4.x; u.x -= vt; } else { o4.x = 0.0f; }
        u.y = TAU * u.y + x4.y;
        if (u.y >= vt) { o4.y = m4.y; u.y -= vt; } else { o4.y = 0.0f; }
        u.z = TAU * u.z + x4.z;
        if (u.z >= vt) { o4.z = m4.z; u.z -= vt; } else { o4.z = 0.0f; }
        u.w = TAU * u.w + x4.w;
        if (u.w >= vt) { o4.w = m4.w; u.w -= vt; } else { o4.w = 0.0f; }

        *(v4f*)(out + (size_t)nb * CHW + rem) = o4;   // plain cached store
    }
}

extern "C" void kernel_launch(void* const* d_in, const int* in_sizes, int n_in,
                              void* d_out, int out_size, void* d_ws, size_t ws_size,
                              hipStream_t stream) {
    const float* x          = (const float*)d_in[0];   // [N, C, H, W]
    const float* vth        = (const float*)d_in[1];   // [N]
    const float* mask_noise = (const float*)d_in[2];   // [N, H, W]
    float* out = (float*)d_out;                        // [N, C, H, W]
    float* bm  = (float*)d_ws;                         // [N, H, W] scratch (2.62 MB)

    block_mask_kernel<<<N * 4, 256, 0, stream>>>(mask_noise, bm);

    const int nvec   = (BS * CHW) / 4;    // 2,097,152 float4 threads
    const int blocks = nvec / 256;        // 8192 blocks
    lif_kernel<<<blocks, 256, 0, stream>>>(x, vth, bm, out);
}